// Round 2
// baseline (262.700 us; speedup 1.0000x reference)
//
#include <hip/hip_runtime.h>
#include <math.h>

#define IN_CAP_N   1152          // floats per row
#define ROW_F4     288           // float4 per row (1152/4)
#define IN_CAP_SZ  5
#define OUT_CAP_N  55
#define NBATCH     8192
#define WAVES_PER_BLOCK 4

// One WAVE per batch element. Each wave:
//   1. preloads W into 4.5 float4 registers (lane-strided),
//   2. computes the 5 dot products u[b,i,:].W via coalesced float4 loads
//      + xor-butterfly reduce (all lanes end with h[i]),
//   3. runs 2-iteration routing with lane j owning out-capsule j,
//   4. writes v[b, 0..54].
// No LDS, no __syncthreads, no inter-wave dependencies.
__global__ __launch_bounds__(256) void digitcaps_fused(
    const float* __restrict__ u,      // (B, 5, 1152)
    const float* __restrict__ W,      // (1152,)
    const float* __restrict__ bparam, // (55,)
    float* __restrict__ out)          // (B, 55)
{
    const int lane = threadIdx.x & 63;
    const int wave = threadIdx.x >> 6;
    const int b    = blockIdx.x * WAVES_PER_BLOCK + wave;   // 0..8191

    // ---- preload W fragments for this lane's strided positions ----------
    const float4* W4 = (const float4*)W;
    float4 wreg[5];
    #pragma unroll
    for (int p = 0; p < 4; ++p) wreg[p] = W4[p * 64 + lane];
    wreg[4] = (lane < 32) ? W4[256 + lane] : make_float4(0.f, 0.f, 0.f, 0.f);

    // ---- 5 row dots, all in this wave -----------------------------------
    const float4* u4 = (const float4*)(u + (size_t)b * (IN_CAP_SZ * IN_CAP_N));
    float h[IN_CAP_SZ];
    #pragma unroll
    for (int i = 0; i < IN_CAP_SZ; ++i) {
        const float4* row = u4 + i * ROW_F4;
        float acc = 0.f;
        #pragma unroll
        for (int p = 0; p < 4; ++p) {
            float4 uv = row[p * 64 + lane];
            acc += uv.x * wreg[p].x + uv.y * wreg[p].y
                 + uv.z * wreg[p].z + uv.w * wreg[p].w;
        }
        if (lane < 32) {
            float4 uv = row[256 + lane];
            acc += uv.x * wreg[4].x + uv.y * wreg[4].y
                 + uv.z * wreg[4].z + uv.w * wreg[4].w;
        }
        #pragma unroll
        for (int off = 32; off > 0; off >>= 1)
            acc += __shfl_xor(acc, off, 64);
        h[i] = acc;   // every lane holds the full dot
    }

    // ---- routing: lane j in [0,55) owns out-capsule j --------------------
    const bool active = (lane < OUT_CAP_N);
    float binit = active ? bparam[lane] : 0.f;
    float bij[IN_CAP_SZ];
    #pragma unroll
    for (int i = 0; i < IN_CAP_SZ; ++i) bij[i] = binit;

    float v = 0.f;
    #pragma unroll
    for (int it = 0; it < 2; ++it) {
        float c[IN_CAP_SZ];
        #pragma unroll
        for (int i = 0; i < IN_CAP_SZ; ++i) {
            float x = active ? bij[i] : -INFINITY;
            float m = x;
            #pragma unroll
            for (int off = 32; off > 0; off >>= 1)
                m = fmaxf(m, __shfl_xor(m, off, 64));
            float e = active ? __expf(bij[i] - m) : 0.f;
            float sum = e;
            #pragma unroll
            for (int off = 32; off > 0; off >>= 1)
                sum += __shfl_xor(sum, off, 64);
            c[i] = e / sum;
        }
        float s = 0.f;
        #pragma unroll
        for (int i = 0; i < IN_CAP_SZ; ++i) s += c[i] * h[i];
        // squash (OUT_CAP_SZ == 1): v = |s| * s / (1 + s^2)
        v = fabsf(s) * s / (1.f + s * s);
        #pragma unroll
        for (int i = 0; i < IN_CAP_SZ; ++i) bij[i] += v * h[i];
    }
    if (active) out[(size_t)b * OUT_CAP_N + lane] = v;
}

extern "C" void kernel_launch(void* const* d_in, const int* in_sizes, int n_in,
                              void* d_out, int out_size, void* d_ws, size_t ws_size,
                              hipStream_t stream) {
    const float* u  = (const float*)d_in[0];
    const float* W  = (const float*)d_in[1];
    const float* bp = (const float*)d_in[2];
    float* out = (float*)d_out;
    digitcaps_fused<<<NBATCH / WAVES_PER_BLOCK, WAVES_PER_BLOCK * 64, 0, stream>>>(u, W, bp, out);
}

// Round 4
// 243.549 us; speedup vs baseline: 1.0786x; 1.0786x over previous
//
#include <hip/hip_runtime.h>
#include <math.h>

#define IN_CAP_N   1152          // floats per row
#define ROW_F4     288           // float4 per row (1152/4)
#define IN_CAP_SZ  5
#define OUT_CAP_N  55
#define NBATCH     8192
#define WAVES_PER_BLOCK 4

typedef float f32x4 __attribute__((ext_vector_type(4)));   // native vector: nt-builtin OK

// One WAVE per batch element; u loads are nontemporal (pure streaming).
__global__ __launch_bounds__(256) void digitcaps_fused(
    const float* __restrict__ u,      // (B, 5, 1152)
    const float* __restrict__ W,      // (1152,)
    const float* __restrict__ bparam, // (55,)
    float* __restrict__ out)          // (B, 55)
{
    const int lane = threadIdx.x & 63;
    const int wave = threadIdx.x >> 6;
    const int b    = blockIdx.x * WAVES_PER_BLOCK + wave;   // 0..8191

    // ---- preload W fragments for this lane's strided positions ----------
    const f32x4* W4 = (const f32x4*)W;
    f32x4 wreg[5];
    #pragma unroll
    for (int p = 0; p < 4; ++p) wreg[p] = W4[p * 64 + lane];
    wreg[4] = (lane < 32) ? W4[256 + lane] : (f32x4){0.f, 0.f, 0.f, 0.f};

    // ---- 5 row dots, all in this wave -----------------------------------
    const f32x4* u4 = (const f32x4*)(u + (size_t)b * (IN_CAP_SZ * IN_CAP_N));
    float h[IN_CAP_SZ];
    #pragma unroll
    for (int i = 0; i < IN_CAP_SZ; ++i) {
        const f32x4* row = u4 + i * ROW_F4;
        // issue all loads for this row up front (nontemporal, streaming)
        f32x4 uv[4];
        #pragma unroll
        for (int p = 0; p < 4; ++p)
            uv[p] = __builtin_nontemporal_load(&row[p * 64 + lane]);
        f32x4 ut = {0.f, 0.f, 0.f, 0.f};
        if (lane < 32)
            ut = __builtin_nontemporal_load(&row[256 + lane]);

        float acc0 = 0.f, acc1 = 0.f;
        #pragma unroll
        for (int p = 0; p < 4; ++p) {
            acc0 += uv[p].x * wreg[p].x + uv[p].y * wreg[p].y;
            acc1 += uv[p].z * wreg[p].z + uv[p].w * wreg[p].w;
        }
        acc0 += ut.x * wreg[4].x + ut.y * wreg[4].y;
        acc1 += ut.z * wreg[4].z + ut.w * wreg[4].w;
        float acc = acc0 + acc1;
        #pragma unroll
        for (int off = 32; off > 0; off >>= 1)
            acc += __shfl_xor(acc, off, 64);
        h[i] = acc;   // every lane holds the full dot
    }

    // ---- routing: lane j in [0,55) owns out-capsule j --------------------
    const bool active = (lane < OUT_CAP_N);
    float binit = active ? bparam[lane] : 0.f;
    float bij[IN_CAP_SZ];
    #pragma unroll
    for (int i = 0; i < IN_CAP_SZ; ++i) bij[i] = binit;

    float v = 0.f;
    #pragma unroll
    for (int it = 0; it < 2; ++it) {
        float c[IN_CAP_SZ];
        #pragma unroll
        for (int i = 0; i < IN_CAP_SZ; ++i) {
            float x = active ? bij[i] : -INFINITY;
            float m = x;
            #pragma unroll
            for (int off = 32; off > 0; off >>= 1)
                m = fmaxf(m, __shfl_xor(m, off, 64));
            float e = active ? __expf(bij[i] - m) : 0.f;
            float sum = e;
            #pragma unroll
            for (int off = 32; off > 0; off >>= 1)
                sum += __shfl_xor(sum, off, 64);
            c[i] = e / sum;
        }
        float s = 0.f;
        #pragma unroll
        for (int i = 0; i < IN_CAP_SZ; ++i) s += c[i] * h[i];
        // squash (OUT_CAP_SZ == 1): v = |s| * s / (1 + s^2)
        v = fabsf(s) * s / (1.f + s * s);
        #pragma unroll
        for (int i = 0; i < IN_CAP_SZ; ++i) bij[i] += v * h[i];
    }
    if (active)
        __builtin_nontemporal_store(v, &out[(size_t)b * OUT_CAP_N + lane]);
}

extern "C" void kernel_launch(void* const* d_in, const int* in_sizes, int n_in,
                              void* d_out, int out_size, void* d_ws, size_t ws_size,
                              hipStream_t stream) {
    const float* u  = (const float*)d_in[0];
    const float* W  = (const float*)d_in[1];
    const float* bp = (const float*)d_in[2];
    float* out = (float*)d_out;
    digitcaps_fused<<<NBATCH / WAVES_PER_BLOCK, WAVES_PER_BLOCK * 64, 0, stream>>>(u, W, bp, out);
}